// Round 4
// baseline (707.055 us; speedup 1.0000x reference)
//
#include <hip/hip_runtime.h>
#include <stdint.h>

#define TOK 2048   // B*S tokens
#define HD  2048   // hidden
#define ID  8192   // dense intermediate
#define MID 1024   // moe intermediate
#define NE  8      // experts
#define KSPLIT 4   // split-K ways for dense down GEMM

typedef __attribute__((ext_vector_type(8))) short s16x8;
typedef __attribute__((ext_vector_type(4))) short s16x4;
typedef __attribute__((ext_vector_type(4))) float f32x4;

constexpr float EPSF  = 1e-6f;
constexpr float ROOTF = 0.02209708691207961f;  // 2048^-0.5

#define MFMA(a, b, c) __builtin_amdgcn_mfma_f32_16x16x32_bf16(a, b, c, 0, 0, 0)

// raw barrier (no implicit vmcnt/lgkmcnt drain, unlike __syncthreads)
#define BAR() __builtin_amdgcn_s_barrier()
// counted vmem wait; memory clobber pins surrounding memory ops
#define VMCNT(n) asm volatile("s_waitcnt vmcnt(" #n ")" ::: "memory")
// drain LDS reads; sched_barrier pins backend scheduling (rule 18)
#define LGKM0() do { asm volatile("s_waitcnt lgkmcnt(0)" ::: "memory"); \
                     __builtin_amdgcn_sched_barrier(0); } while (0)

// async global->LDS, 16 B per lane. LDS dest must be wave-uniform base;
// HW writes base + lane*16. Global src is per-lane.
__device__ __forceinline__ void gload16(const void* g, void* l) {
  __builtin_amdgcn_global_load_lds(
      (const __attribute__((address_space(1))) void*)g,
      (__attribute__((address_space(3))) void*)l, 16, 0, 0);
}

__device__ __forceinline__ short f2bf(float f) {
  union { float f; uint32_t u; } v; v.f = f;
  uint32_t r = v.u + 0x7fffu + ((v.u >> 16) & 1u);   // RNE
  return (short)(r >> 16);
}

__device__ __forceinline__ float gelu_tanh(float x) {
  float x3 = x * x * x;
  float u = 0.7978845608028654f * (x + 0.044715f * x3);
  return 0.5f * x * (1.0f + tanhf(u));
}

// ---------------- K1: RMSNorms (pre1/pre2) + router + top-2 gather -------
__global__ __launch_bounds__(256) void k_rms_router(
    const float* __restrict__ x, const float* __restrict__ rnp1,
    const float* __restrict__ rnp2, const float* __restrict__ rsc,
    const float* __restrict__ rw, const float* __restrict__ pes,
    short* __restrict__ rms1, short* __restrict__ rms2,
    int* __restrict__ cnt, int* __restrict__ tokl,
    float* __restrict__ wgtl, int* __restrict__ slotl) {
  const int t = blockIdx.x, tid = threadIdx.x;
  const size_t base = (size_t)t * HD;
  f32x4 v[2];
  float ss = 0.f;
#pragma unroll
  for (int i = 0; i < 2; ++i) {
    v[i] = *(const f32x4*)(x + base + tid * 4 + i * 1024);
#pragma unroll
    for (int j = 0; j < 4; ++j) ss += v[i][j] * v[i][j];
  }
  __shared__ float sr[4];
  __shared__ float sl[32];
#pragma unroll
  for (int off = 32; off; off >>= 1) ss += __shfl_down(ss, off, 64);
  if ((tid & 63) == 0) sr[tid >> 6] = ss;
  __syncthreads();
  const float inv = rsqrtf((sr[0] + sr[1] + sr[2] + sr[3]) * (1.0f / HD) + EPSF);
  float p[8] = {0, 0, 0, 0, 0, 0, 0, 0};
#pragma unroll
  for (int i = 0; i < 2; ++i) {
    const int h = tid * 4 + i * 1024;
    f32x4 w1 = *(const f32x4*)(rnp1 + h);
    f32x4 w2 = *(const f32x4*)(rnp2 + h);
    f32x4 sc = *(const f32x4*)(rsc + h);
    s16x4 o1, o2;
#pragma unroll
    for (int j = 0; j < 4; ++j) {
      float xn = v[i][j] * inv;
      o1[j] = f2bf(xn * w1[j]);
      o2[j] = f2bf(xn * w2[j]);
      float xq = xn * sc[j] * ROOTF;
      const float* rr = rw + (size_t)(h + j) * NE;
      f32x4 ra = *(const f32x4*)rr;
      f32x4 rb = *(const f32x4*)(rr + 4);
      p[0] += xq * ra[0]; p[1] += xq * ra[1]; p[2] += xq * ra[2]; p[3] += xq * ra[3];
      p[4] += xq * rb[0]; p[5] += xq * rb[1]; p[6] += xq * rb[2]; p[7] += xq * rb[3];
    }
    *(s16x4*)(rms1 + base + h) = o1;
    *(s16x4*)(rms2 + base + h) = o2;
  }
#pragma unroll
  for (int e = 0; e < 8; ++e)
#pragma unroll
    for (int off = 32; off; off >>= 1) p[e] += __shfl_down(p[e], off, 64);
  if ((tid & 63) == 0) {
#pragma unroll
    for (int e = 0; e < 8; ++e) sl[(tid >> 6) * 8 + e] = p[e];
  }
  __syncthreads();
  if (tid == 0) {
    float l[8];
#pragma unroll
    for (int e = 0; e < 8; ++e) l[e] = sl[e] + sl[8 + e] + sl[16 + e] + sl[24 + e];
    int i1 = 0;
#pragma unroll
    for (int e = 1; e < 8; ++e) if (l[e] > l[i1]) i1 = e;
    int i2 = (i1 == 0) ? 1 : 0;
#pragma unroll
    for (int e = 0; e < 8; ++e) if (e != i1 && l[e] > l[i2]) i2 = e;
    float p2 = expf(l[i2] - l[i1]);     // p1 = 1
    float s = 1.0f + p2;
    float w1 = (1.0f / s) * pes[i1];
    float w2 = (p2 / s) * pes[i2];
    int q1 = atomicAdd(&cnt[i1], 1);
    tokl[i1 * TOK + q1] = t; wgtl[i1 * TOK + q1] = w1; slotl[i1 * TOK + q1] = 0;
    int q2 = atomicAdd(&cnt[i2], 1);
    tokl[i2 * TOK + q2] = t; wgtl[i2 * TOK + q2] = w2; slotl[i2 * TOK + q2] = 1;
  }
}

// ---------------- K2: fp32 (R,C) -> bf16 (C,R) transpose-convert ---------
__global__ __launch_bounds__(256) void k_transpose(
    const float* __restrict__ in, short* __restrict__ out, int R, int C) {
  __shared__ float tile[64 * 65];
  const int tid = threadIdx.x;
  const int c0 = blockIdx.x * 64, r0 = blockIdx.y * 64;
  const size_t bo = (size_t)blockIdx.z * R * C;
#pragma unroll
  for (int i = 0; i < 4; ++i) {
    int idx = tid + 256 * i;
    int r = idx >> 4, c4 = idx & 15;
    f32x4 f = *(const f32x4*)(in + bo + (size_t)(r0 + r) * C + c0 + c4 * 4);
#pragma unroll
    for (int j = 0; j < 4; ++j) tile[(c4 * 4 + j) * 65 + r] = f[j];
  }
  __syncthreads();
#pragma unroll
  for (int i = 0; i < 2; ++i) {
    int ch = tid + 256 * i;
    int c = ch >> 3, rs = ch & 7;
    s16x8 o;
#pragma unroll
    for (int q = 0; q < 8; ++q) o[q] = f2bf(tile[c * 65 + rs * 8 + q]);
    *(s16x8*)(out + bo + (size_t)(c0 + c) * R + r0 + rs * 8) = o;
  }
}

// ---------------- K3: dense gate+up GEMM, pipelined, fused epilogue ------
// block = 64 i x 128 t (gate+up stacked in LDS), 4 waves, 16 MFMA/K-step.
__global__ __launch_bounds__(256) void k_dense_gateup(
    const short* __restrict__ wgT, const short* __restrict__ wuT,  // [I][H]
    const short* __restrict__ xin,                                  // [T][H]
    short* __restrict__ act) {                                      // [T][I]
  __shared__ short sW[3][128 * 32];
  __shared__ short sX[3][128 * 32];
  const int tid = threadIdx.x;
  const int n0 = blockIdx.x * 64, t0 = blockIdx.y * 128;
  const int lane = tid & 63, wave = tid >> 6;
  const int ln15 = lane & 15, k8 = (lane >> 4) * 8;
  const int nsub = (wave & 1) * 32, tsub = (wave >> 1) * 64;
  const int srow = tid >> 2, skc = (tid & 3) * 8;
  const short* gW0 = wgT + (size_t)(n0 + srow) * HD + skc;
  const short* gW1 = wuT + (size_t)(n0 + srow) * HD + skc;
  const short* gX0 = xin + (size_t)(t0 + srow) * HD + skc;
  const short* gX1 = xin + (size_t)(t0 + 64 + srow) * HD + skc;
  const int NT = HD / 32;
  auto STAGE = [&](int kt, int b) {
    const int ko = kt * 32;
    char* lW = (char*)sW[b] + wave * 1024;
    char* lX = (char*)sX[b] + wave * 1024;
    gload16(gW0 + ko, lW);
    gload16(gW1 + ko, lW + 4096);
    gload16(gX0 + ko, lX);
    gload16(gX1 + ko, lX + 4096);
  };
  f32x4 accg[2][4], accu[2][4];
#pragma unroll
  for (int m = 0; m < 2; ++m)
#pragma unroll
    for (int n = 0; n < 4; ++n) { accg[m][n] = (f32x4)0.f; accu[m][n] = (f32x4)0.f; }
  STAGE(0, 0); STAGE(1, 1);
  VMCNT(4);
  BAR();
  int bc = 0, bs = 2;
  for (int kt = 0; kt < NT; ++kt) {
    if (kt + 2 < NT)      { STAGE(kt + 2, bs); VMCNT(8); }
    else if (kt + 1 < NT) { VMCNT(4); }
    else                  { VMCNT(0); }
    BAR();   // barrier A: tile kt resident for all waves
    s16x8 ag[2], au[2], bx[4];
#pragma unroll
    for (int m = 0; m < 2; ++m) {
      ag[m] = *(const s16x8*)(sW[bc] + (nsub + m * 16 + ln15) * 32 + k8);
      au[m] = *(const s16x8*)(sW[bc] + (64 + nsub + m * 16 + ln15) * 32 + k8);
    }
#pragma unroll
    for (int n = 0; n < 4; ++n)
      bx[n] = *(const s16x8*)(sX[bc] + (tsub + n * 16 + ln15) * 32 + k8);
    LGKM0();
    BAR();   // barrier B: all reads of buf bc done -> it may be restaged
#pragma unroll
    for (int m = 0; m < 2; ++m)
#pragma unroll
      for (int n = 0; n < 4; ++n) {
        accg[m][n] = MFMA(ag[m], bx[n], accg[m][n]);
        accu[m][n] = MFMA(au[m], bx[n], accu[m][n]);
      }
    bc = (bc == 2) ? 0 : bc + 1;
    bs = (bs == 2) ? 0 : bs + 1;
  }
#pragma unroll
  for (int m = 0; m < 2; ++m)
#pragma unroll
    for (int n = 0; n < 4; ++n) {
      const int t = t0 + tsub + n * 16 + ln15;
      const int ib = n0 + nsub + m * 16 + (lane >> 4) * 4;
      s16x4 o;
#pragma unroll
      for (int r = 0; r < 4; ++r)
        o[r] = f2bf(gelu_tanh(accg[m][n][r]) * accu[m][n][r]);
      *(s16x4*)(act + (size_t)t * ID + ib) = o;
    }
}

// ------- K4: dense down GEMM, split-K x4, pipelined (128x128 tile) -------
__global__ __launch_bounds__(256) void k_dense_down(
    const short* __restrict__ wdT,   // [H][I]
    const short* __restrict__ act,   // [T][I]
    float* __restrict__ dparts) {    // [KSPLIT][T][H]
  __shared__ short sW[3][128 * 32];
  __shared__ short sX[3][128 * 32];
  const int tid = threadIdx.x;
  const int n0 = blockIdx.x * 128, t0 = blockIdx.y * 128;
  const int kbase = blockIdx.z * (ID / KSPLIT);
  const int lane = tid & 63, wave = tid >> 6;
  const int wr = wave >> 1, wc = wave & 1;
  const int ln15 = lane & 15, k8 = (lane >> 4) * 8;
  const int srow = tid >> 2, skc = (tid & 3) * 8;
  const short* gW0 = wdT + (size_t)(n0 + srow) * ID + kbase + skc;
  const short* gW1 = wdT + (size_t)(n0 + 64 + srow) * ID + kbase + skc;
  const short* gX0 = act + (size_t)(t0 + srow) * ID + kbase + skc;
  const short* gX1 = act + (size_t)(t0 + 64 + srow) * ID + kbase + skc;
  const int NT = ID / KSPLIT / 32;
  auto STAGE = [&](int kt, int b) {
    const int ko = kt * 32;
    char* lW = (char*)sW[b] + wave * 1024;
    char* lX = (char*)sX[b] + wave * 1024;
    gload16(gW0 + ko, lW);
    gload16(gW1 + ko, lW + 4096);
    gload16(gX0 + ko, lX);
    gload16(gX1 + ko, lX + 4096);
  };
  f32x4 acc[4][4];
#pragma unroll
  for (int m = 0; m < 4; ++m)
#pragma unroll
    for (int n = 0; n < 4; ++n) acc[m][n] = (f32x4)0.f;
  STAGE(0, 0); STAGE(1, 1);
  VMCNT(4);
  BAR();
  int bc = 0, bs = 2;
  for (int kt = 0; kt < NT; ++kt) {
    if (kt + 2 < NT)      { STAGE(kt + 2, bs); VMCNT(8); }
    else if (kt + 1 < NT) { VMCNT(4); }
    else                  { VMCNT(0); }
    BAR();
    s16x8 a[4], b[4];
#pragma unroll
    for (int m = 0; m < 4; ++m)
      a[m] = *(const s16x8*)(sW[bc] + (wr * 64 + m * 16 + ln15) * 32 + k8);
#pragma unroll
    for (int n = 0; n < 4; ++n)
      b[n] = *(const s16x8*)(sX[bc] + (wc * 64 + n * 16 + ln15) * 32 + k8);
    LGKM0();
    BAR();
#pragma unroll
    for (int m = 0; m < 4; ++m)
#pragma unroll
      for (int n = 0; n < 4; ++n) acc[m][n] = MFMA(a[m], b[n], acc[m][n]);
    bc = (bc == 2) ? 0 : bc + 1;
    bs = (bs == 2) ? 0 : bs + 1;
  }
  float* dst = dparts + (size_t)blockIdx.z * TOK * HD;
#pragma unroll
  for (int n = 0; n < 4; ++n) {
    const int t = t0 + wc * 64 + n * 16 + ln15;
#pragma unroll
    for (int m = 0; m < 4; ++m) {
      const int h = n0 + wr * 64 + m * 16 + (lane >> 4) * 4;
      *(f32x4*)(dst + (size_t)t * HD + h) = acc[m][n];
    }
  }
}

// ---------------- K5: expert gate+up GEMM (gathered), pipelined ----------
__global__ __launch_bounds__(256) void k_exp_gateup(
    const short* __restrict__ wegT, const short* __restrict__ weuT,  // [E][MI][H]
    const short* __restrict__ rms2,                                   // [T][H]
    const int* __restrict__ cnt, const int* __restrict__ tokl,
    short* __restrict__ acte) {                                       // [E][T][MI]
  const int e = blockIdx.z;
  const int cn = cnt[e];
  const int t0 = blockIdx.y * 128;
  if (t0 >= cn) return;
  const int n0 = blockIdx.x * 64;
  __shared__ short sW[3][128 * 32];
  __shared__ short sX[3][128 * 32];
  const int tid = threadIdx.x;
  const int lane = tid & 63, wave = tid >> 6;
  const int ln15 = lane & 15, k8 = (lane >> 4) * 8;
  const int nsub = (wave & 1) * 32, tsub = (wave >> 1) * 64;
  const int srow = tid >> 2, skc = (tid & 3) * 8;
  const int* tl = tokl + e * TOK;
  int r0 = t0 + srow, r1 = t0 + 64 + srow;
  int tk0 = tl[r0 < cn ? r0 : cn - 1];
  int tk1 = tl[r1 < cn ? r1 : cn - 1];
  const short* gW0 = wegT + (size_t)e * MID * HD + (size_t)(n0 + srow) * HD + skc;
  const short* gW1 = weuT + (size_t)e * MID * HD + (size_t)(n0 + srow) * HD + skc;
  const short* gX0 = rms2 + (size_t)tk0 * HD + skc;
  const short* gX1 = rms2 + (size_t)tk1 * HD + skc;
  const int NT = HD / 32;
  auto STAGE = [&](int kt, int b) {
    const int ko = kt * 32;
    char* lW = (char*)sW[b] + wave * 1024;
    char* lX = (char*)sX[b] + wave * 1024;
    gload16(gW0 + ko, lW);
    gload16(gW1 + ko, lW + 4096);
    gload16(gX0 + ko, lX);
    gload16(gX1 + ko, lX + 4096);
  };
  f32x4 accg[2][4], accu[2][4];
#pragma unroll
  for (int m = 0; m < 2; ++m)
#pragma unroll
    for (int n = 0; n < 4; ++n) { accg[m][n] = (f32x4)0.f; accu[m][n] = (f32x4)0.f; }
  STAGE(0, 0); STAGE(1, 1);
  VMCNT(4);
  BAR();
  int bc = 0, bs = 2;
  for (int kt = 0; kt < NT; ++kt) {
    if (kt + 2 < NT)      { STAGE(kt + 2, bs); VMCNT(8); }
    else if (kt + 1 < NT) { VMCNT(4); }
    else                  { VMCNT(0); }
    BAR();
    s16x8 ag[2], au[2], bx[4];
#pragma unroll
    for (int m = 0; m < 2; ++m) {
      ag[m] = *(const s16x8*)(sW[bc] + (nsub + m * 16 + ln15) * 32 + k8);
      au[m] = *(const s16x8*)(sW[bc] + (64 + nsub + m * 16 + ln15) * 32 + k8);
    }
#pragma unroll
    for (int n = 0; n < 4; ++n)
      bx[n] = *(const s16x8*)(sX[bc] + (tsub + n * 16 + ln15) * 32 + k8);
    LGKM0();
    BAR();
#pragma unroll
    for (int m = 0; m < 2; ++m)
#pragma unroll
      for (int n = 0; n < 4; ++n) {
        accg[m][n] = MFMA(ag[m], bx[n], accg[m][n]);
        accu[m][n] = MFMA(au[m], bx[n], accu[m][n]);
      }
    bc = (bc == 2) ? 0 : bc + 1;
    bs = (bs == 2) ? 0 : bs + 1;
  }
#pragma unroll
  for (int m = 0; m < 2; ++m)
#pragma unroll
    for (int n = 0; n < 4; ++n) {
      const int r = t0 + tsub + n * 16 + ln15;
      if (r < cn) {
        const int ib = n0 + nsub + m * 16 + (lane >> 4) * 4;
        s16x4 o;
#pragma unroll
        for (int q = 0; q < 4; ++q)
          o[q] = f2bf(gelu_tanh(accg[m][n][q]) * accu[m][n][q]);
        *(s16x4*)(acte + (size_t)e * TOK * MID + (size_t)r * MID + ib) = o;
      }
    }
}

// ---------------- K6: expert down GEMM, pipelined + weighted scatter -----
__global__ __launch_bounds__(256) void k_exp_down(
    const short* __restrict__ wedT,   // [E][H][MI]
    const short* __restrict__ acte,   // [E][T][MI]
    const int* __restrict__ cnt, const int* __restrict__ tokl,
    const float* __restrict__ wgtl, const int* __restrict__ slotl,
    float* __restrict__ moep) {       // [2][T][H]
  const int e = blockIdx.z;
  const int cn = cnt[e];
  const int t0 = blockIdx.y * 128;
  if (t0 >= cn) return;
  const int n0 = blockIdx.x * 128;
  __shared__ short sW[3][128 * 32];
  __shared__ short sX[3][128 * 32];
  const int tid = threadIdx.x;
  const int lane = tid & 63, wave = tid >> 6;
  const int wr = wave >> 1, wc = wave & 1;
  const int ln15 = lane & 15, k8 = (lane >> 4) * 8;
  const int srow = tid >> 2, skc = (tid & 3) * 8;
  const short* wb = wedT + (size_t)e * HD * MID;
  const short* gW0 = wb + (size_t)(n0 + srow) * MID + skc;
  const short* gW1 = wb + (size_t)(n0 + 64 + srow) * MID + skc;
  const short* ab = acte + (size_t)e * TOK * MID;
  const short* gX0 = ab + (size_t)(t0 + srow) * MID + skc;
  const short* gX1 = ab + (size_t)(t0 + 64 + srow) * MID + skc;
  const int NT = MID / 32;
  auto STAGE = [&](int kt, int b) {
    const int ko = kt * 32;
    char* lW = (char*)sW[b] + wave * 1024;
    char* lX = (char*)sX[b] + wave * 1024;
    gload16(gW0 + ko, lW);
    gload16(gW1 + ko, lW + 4096);
    gload16(gX0 + ko, lX);
    gload16(gX1 + ko, lX + 4096);
  };
  f32x4 acc[4][4];
#pragma unroll
  for (int m = 0; m < 4; ++m)
#pragma unroll
    for (int n = 0; n < 4; ++n) acc[m][n] = (f32x4)0.f;
  STAGE(0, 0); STAGE(1, 1);
  VMCNT(4);
  BAR();
  int bc = 0, bs = 2;
  for (int kt = 0; kt < NT; ++kt) {
    if (kt + 2 < NT)      { STAGE(kt + 2, bs); VMCNT(8); }
    else if (kt + 1 < NT) { VMCNT(4); }
    else                  { VMCNT(0); }
    BAR();
    s16x8 a[4], b[4];
#pragma unroll
    for (int m = 0; m < 4; ++m)
      a[m] = *(const s16x8*)(sW[bc] + (wr * 64 + m * 16 + ln15) * 32 + k8);
#pragma unroll
    for (int n = 0; n < 4; ++n)
      b[n] = *(const s16x8*)(sX[bc] + (wc * 64 + n * 16 + ln15) * 32 + k8);
    LGKM0();
    BAR();
#pragma unroll
    for (int m = 0; m < 4; ++m)
#pragma unroll
      for (int n = 0; n < 4; ++n) acc[m][n] = MFMA(a[m], b[n], acc[m][n]);
    bc = (bc == 2) ? 0 : bc + 1;
    bs = (bs == 2) ? 0 : bs + 1;
  }
#pragma unroll
  for (int n = 0; n < 4; ++n) {
    const int r = t0 + wc * 64 + n * 16 + ln15;
    if (r < cn) {
      const int tk = tokl[e * TOK + r];
      const float wf = wgtl[e * TOK + r];
      const int sl = slotl[e * TOK + r];
      float* dst = moep + (size_t)sl * TOK * HD + (size_t)tk * HD;
#pragma unroll
      for (int m = 0; m < 4; ++m) {
        const int h = n0 + wr * 64 + m * 16 + (lane >> 4) * 4;
        f32x4 v = acc[m][n] * wf;
        *(f32x4*)(dst + h) = v;
      }
    }
  }
}

// ---------------- K7: final triple RMSNorm fusion ------------------------
__global__ __launch_bounds__(256) void k_final(
    const float* __restrict__ dparts, const float* __restrict__ moep,
    const float* __restrict__ rno1, const float* __restrict__ rno2,
    const float* __restrict__ rnof, float* __restrict__ out) {
  const int t = blockIdx.x, tid = threadIdx.x;
  const size_t base = (size_t)t * HD;
  f32x4 dv[2], mv[2];
  float ssd = 0.f, ssm = 0.f;
#pragma unroll
  for (int i = 0; i < 2; ++i) {
    const int h = tid * 4 + i * 1024;
    dv[i] = (f32x4)0.f;
#pragma unroll
    for (int z = 0; z < KSPLIT; ++z)
      dv[i] += *(const f32x4*)(dparts + (size_t)z * TOK * HD + base + h);
    f32x4 a = *(const f32x4*)(moep + base + h);
    f32x4 b = *(const f32x4*)(moep + (size_t)TOK * HD + base + h);
    mv[i] = a + b;
#pragma unroll
    for (int j = 0; j < 4; ++j) { ssd += dv[i][j] * dv[i][j]; ssm += mv[i][j] * mv[i][j]; }
  }
  __shared__ float sr[8];
#pragma unroll
  for (int off = 32; off; off >>= 1) {
    ssd += __shfl_down(ssd, off, 64);
    ssm += __shfl_down(ssm, off, 64);
  }
  if ((tid & 63) == 0) { sr[tid >> 6] = ssd; sr[4 + (tid >> 6)] = ssm; }
  __syncthreads();
  const float invd = rsqrtf((sr[0] + sr[1] + sr[2] + sr[3]) * (1.0f / HD) + EPSF);
  const float invm = rsqrtf((sr[4] + sr[5] + sr[6] + sr[7]) * (1.0f / HD) + EPSF);
  f32x4 y[2];
  float ssy = 0.f;
#pragma unroll
  for (int i = 0; i < 2; ++i) {
    const int h = tid * 4 + i * 1024;
    f32x4 w1 = *(const f32x4*)(rno1 + h);
    f32x4 w2 = *(const f32x4*)(rno2 + h);
#pragma unroll
    for (int j = 0; j < 4; ++j) {
      y[i][j] = dv[i][j] * invd * w1[j] + mv[i][j] * invm * w2[j];
      ssy += y[i][j] * y[i][j];
    }
  }
  __syncthreads();
#pragma unroll
  for (int off = 32; off; off >>= 1) ssy += __shfl_down(ssy, off, 64);
  if ((tid & 63) == 0) sr[tid >> 6] = ssy;
  __syncthreads();
  const float invy = rsqrtf((sr[0] + sr[1] + sr[2] + sr[3]) * (1.0f / HD) + EPSF);
#pragma unroll
  for (int i = 0; i < 2; ++i) {
    const int h = tid * 4 + i * 1024;
    f32x4 w = *(const f32x4*)(rnof + h);
    f32x4 o;
#pragma unroll
    for (int j = 0; j < 4; ++j) o[j] = y[i][j] * invy * w[j];
    *(f32x4*)(out + base + h) = o;
  }
}

// ---------------- launcher ----------------------------------------------
extern "C" void kernel_launch(void* const* d_in, const int* in_sizes, int n_in,
                              void* d_out, int out_size, void* d_ws, size_t ws_size,
                              hipStream_t stream) {
  (void)in_sizes; (void)n_in; (void)out_size;
  const float* x    = (const float*)d_in[0];
  const float* rnp1 = (const float*)d_in[1];
  const float* rnp2 = (const float*)d_in[2];
  const float* rno1 = (const float*)d_in[3];
  const float* rno2 = (const float*)d_in[4];
  const float* rnof = (const float*)d_in[5];
  const float* wg   = (const float*)d_in[6];
  const float* wu   = (const float*)d_in[7];
  const float* wd   = (const float*)d_in[8];
  const float* rw   = (const float*)d_in[9];
  const float* rsc  = (const float*)d_in[10];
  const float* pes  = (const float*)d_in[11];
  const float* weg  = (const float*)d_in[12];
  const float* weu  = (const float*)d_in[13];
  const float* wed  = (const float*)d_in[14];
  float* out = (float*)d_out;

  char* ws = (char*)d_ws;
  size_t off = 0;
  auto alloc = [&](size_t bytes) -> void* {
    void* p = ws + off;
    off += (bytes + 255) & ~(size_t)255;
    return p;
  };
  const size_t IH  = (size_t)ID * HD;
  const size_t EMH = (size_t)NE * MID * HD;
  short* wgT   = (short*)alloc(IH * 2);   // NOTE: wgT+wuT (contiguous, 67 MB)
  short* wuT   = (short*)alloc(IH * 2);   //       reused as dparts after gateup
  short* wdT   = (short*)alloc(IH * 2);
  short* wegT  = (short*)alloc(EMH * 2);
  short* weuT  = (short*)alloc(EMH * 2);
  short* wedT  = (short*)alloc(EMH * 2);
  short* rms1  = (short*)alloc((size_t)TOK * HD * 2);
  short* rms2  = (short*)alloc((size_t)TOK * HD * 2);
  short* actb  = (short*)alloc((size_t)TOK * ID * 2);
  short* acte  = (short*)alloc((size_t)NE * TOK * MID * 2);
  float* moep  = (float*)alloc((size_t)2 * TOK * HD * 4);
  int*   cnt   = (int*)alloc(NE * 4);
  int*   tokl  = (int*)alloc((size_t)NE * TOK * 4);
  float* wgtl  = (float*)alloc((size_t)NE * TOK * 4);
  int*   slotl = (int*)alloc((size_t)NE * TOK * 4);
  if (off > ws_size) return;  // workspace too small: bail cleanly
  // dense split-K partials: alias onto wgT/wuT (dead after k_dense_gateup).
  // KSPLIT * TOK * HD * 4 B = 67,108,864 B == exactly the wgT+wuT region.
  float* dparts = (float*)wgT;

  hipMemsetAsync(cnt, 0, NE * 4, stream);
  k_rms_router<<<TOK, 256, 0, stream>>>(x, rnp1, rnp2, rsc, rw, pes,
                                        rms1, rms2, cnt, tokl, wgtl, slotl);
  k_transpose<<<dim3(ID / 64, HD / 64, 1), 256, 0, stream>>>(wg, wgT, HD, ID);
  k_transpose<<<dim3(ID / 64, HD / 64, 1), 256, 0, stream>>>(wu, wuT, HD, ID);
  k_transpose<<<dim3(HD / 64, ID / 64, 1), 256, 0, stream>>>(wd, wdT, ID, HD);
  k_transpose<<<dim3(MID / 64, HD / 64, NE), 256, 0, stream>>>(weg, wegT, HD, MID);
  k_transpose<<<dim3(MID / 64, HD / 64, NE), 256, 0, stream>>>(weu, weuT, HD, MID);
  k_transpose<<<dim3(HD / 64, MID / 64, NE), 256, 0, stream>>>(wed, wedT, MID, HD);
  k_dense_gateup<<<dim3(ID / 64, TOK / 128), 256, 0, stream>>>(wgT, wuT, rms1, actb);
  k_dense_down<<<dim3(HD / 128, TOK / 128, KSPLIT), 256, 0, stream>>>(wdT, actb, dparts);
  k_exp_gateup<<<dim3(MID / 64, TOK / 128, NE), 256, 0, stream>>>(wegT, weuT, rms2,
                                                                  cnt, tokl, acte);
  k_exp_down<<<dim3(HD / 128, TOK / 128, NE), 256, 0, stream>>>(wedT, acte, cnt, tokl,
                                                                wgtl, slotl, moep);
  k_final<<<TOK, 256, 0, stream>>>(dparts, moep, rno1, rno2, rnof, out);
}

// Round 5
// 613.686 us; speedup vs baseline: 1.1521x; 1.1521x over previous
//
#include <hip/hip_runtime.h>
#include <stdint.h>

#define TOK 2048   // B*S tokens
#define HD  2048   // hidden
#define ID  8192   // dense intermediate
#define MID 1024   // moe intermediate
#define NE  8      // experts
#define KSPLIT 4   // split-K ways for dense down GEMM

typedef __attribute__((ext_vector_type(8))) short s16x8;
typedef __attribute__((ext_vector_type(4))) short s16x4;
typedef __attribute__((ext_vector_type(4))) float f32x4;

constexpr float EPSF  = 1e-6f;
constexpr float ROOTF = 0.02209708691207961f;  // 2048^-0.5

#define MFMA(a, b, c) __builtin_amdgcn_mfma_f32_16x16x32_bf16(a, b, c, 0, 0, 0)
#define BAR() __builtin_amdgcn_s_barrier()
#define SCHED0() __builtin_amdgcn_sched_barrier(0)
#define VMCNT(n) asm volatile("s_waitcnt vmcnt(" #n ")" ::: "memory")

// async global->LDS, 16 B per lane. LDS dest must be wave-uniform base;
// HW writes base + lane*16. Global src is per-lane.
__device__ __forceinline__ void gload16(const void* g, void* l) {
  __builtin_amdgcn_global_load_lds(
      (const __attribute__((address_space(1))) void*)g,
      (__attribute__((address_space(3))) void*)l, 16, 0, 0);
}

__device__ __forceinline__ short f2bf(float f) {
  union { float f; uint32_t u; } v; v.f = f;
  uint32_t r = v.u + 0x7fffu + ((v.u >> 16) & 1u);   // RNE
  return (short)(r >> 16);
}

__device__ __forceinline__ float bf2f(short s) {
  union { uint32_t u; float f; } v; v.u = ((uint32_t)(uint16_t)s) << 16;
  return v.f;
}

__device__ __forceinline__ float gelu_tanh(float x) {
  float x3 = x * x * x;
  float u = 0.7978845608028654f * (x + 0.044715f * x3);
  return 0.5f * x * (1.0f + tanhf(u));
}

// ---------------- K1: RMSNorms (pre1/pre2) + router + top-2 gather -------
__global__ __launch_bounds__(256) void k_rms_router(
    const float* __restrict__ x, const float* __restrict__ rnp1,
    const float* __restrict__ rnp2, const float* __restrict__ rsc,
    const float* __restrict__ rw, const float* __restrict__ pes,
    short* __restrict__ rms1, short* __restrict__ rms2,
    int* __restrict__ cnt, int* __restrict__ tokl,
    float* __restrict__ wgtl, int* __restrict__ slotl) {
  const int t = blockIdx.x, tid = threadIdx.x;
  const size_t base = (size_t)t * HD;
  f32x4 v[2];
  float ss = 0.f;
#pragma unroll
  for (int i = 0; i < 2; ++i) {
    v[i] = *(const f32x4*)(x + base + tid * 4 + i * 1024);
#pragma unroll
    for (int j = 0; j < 4; ++j) ss += v[i][j] * v[i][j];
  }
  __shared__ float sr[4];
  __shared__ float sl[32];
#pragma unroll
  for (int off = 32; off; off >>= 1) ss += __shfl_down(ss, off, 64);
  if ((tid & 63) == 0) sr[tid >> 6] = ss;
  __syncthreads();
  const float inv = rsqrtf((sr[0] + sr[1] + sr[2] + sr[3]) * (1.0f / HD) + EPSF);
  float p[8] = {0, 0, 0, 0, 0, 0, 0, 0};
#pragma unroll
  for (int i = 0; i < 2; ++i) {
    const int h = tid * 4 + i * 1024;
    f32x4 w1 = *(const f32x4*)(rnp1 + h);
    f32x4 w2 = *(const f32x4*)(rnp2 + h);
    f32x4 sc = *(const f32x4*)(rsc + h);
    s16x4 o1, o2;
#pragma unroll
    for (int j = 0; j < 4; ++j) {
      float xn = v[i][j] * inv;
      o1[j] = f2bf(xn * w1[j]);
      o2[j] = f2bf(xn * w2[j]);
      float xq = xn * sc[j] * ROOTF;
      const float* rr = rw + (size_t)(h + j) * NE;
      f32x4 ra = *(const f32x4*)rr;
      f32x4 rb = *(const f32x4*)(rr + 4);
      p[0] += xq * ra[0]; p[1] += xq * ra[1]; p[2] += xq * ra[2]; p[3] += xq * ra[3];
      p[4] += xq * rb[0]; p[5] += xq * rb[1]; p[6] += xq * rb[2]; p[7] += xq * rb[3];
    }
    *(s16x4*)(rms1 + base + h) = o1;
    *(s16x4*)(rms2 + base + h) = o2;
  }
#pragma unroll
  for (int e = 0; e < 8; ++e)
#pragma unroll
    for (int off = 32; off; off >>= 1) p[e] += __shfl_down(p[e], off, 64);
  if ((tid & 63) == 0) {
#pragma unroll
    for (int e = 0; e < 8; ++e) sl[(tid >> 6) * 8 + e] = p[e];
  }
  __syncthreads();
  if (tid == 0) {
    float l[8];
#pragma unroll
    for (int e = 0; e < 8; ++e) l[e] = sl[e] + sl[8 + e] + sl[16 + e] + sl[24 + e];
    int i1 = 0;
#pragma unroll
    for (int e = 1; e < 8; ++e) if (l[e] > l[i1]) i1 = e;
    int i2 = (i1 == 0) ? 1 : 0;
#pragma unroll
    for (int e = 0; e < 8; ++e) if (e != i1 && l[e] > l[i2]) i2 = e;
    float p2 = expf(l[i2] - l[i1]);     // p1 = 1
    float s = 1.0f + p2;
    float w1 = (1.0f / s) * pes[i1];
    float w2 = (p2 / s) * pes[i2];
    int q1 = atomicAdd(&cnt[i1], 1);
    tokl[i1 * TOK + q1] = t; wgtl[i1 * TOK + q1] = w1; slotl[i1 * TOK + q1] = 0;
    int q2 = atomicAdd(&cnt[i2], 1);
    tokl[i2 * TOK + q2] = t; wgtl[i2 * TOK + q2] = w2; slotl[i2 * TOK + q2] = 1;
  }
}

// ---------------- K2: fp32 (R,C) -> bf16 (C,R) transpose-convert ---------
__global__ __launch_bounds__(256) void k_transpose(
    const float* __restrict__ in, short* __restrict__ out, int R, int C) {
  __shared__ float tile[64 * 65];
  const int tid = threadIdx.x;
  const int c0 = blockIdx.x * 64, r0 = blockIdx.y * 64;
  const size_t bo = (size_t)blockIdx.z * R * C;
#pragma unroll
  for (int i = 0; i < 4; ++i) {
    int idx = tid + 256 * i;
    int r = idx >> 4, c4 = idx & 15;
    f32x4 f = *(const f32x4*)(in + bo + (size_t)(r0 + r) * C + c0 + c4 * 4);
#pragma unroll
    for (int j = 0; j < 4; ++j) tile[(c4 * 4 + j) * 65 + r] = f[j];
  }
  __syncthreads();
#pragma unroll
  for (int i = 0; i < 2; ++i) {
    int ch = tid + 256 * i;
    int c = ch >> 3, rs = ch & 7;
    s16x8 o;
#pragma unroll
    for (int q = 0; q < 8; ++q) o[q] = f2bf(tile[c * 65 + rs * 8 + q]);
    *(s16x8*)(out + bo + (size_t)(c0 + c) * R + r0 + rs * 8) = o;
  }
}

// ---------------- K3: 256x256 BK=64 deep-pipelined GEMM ------------------
// C[t][i] (bf16, no activation) = X[t][k] * W[i][k]^T.
// 8 waves (2 Mx4 N), per-wave 128x64 out, acc[8][4], 64 MFMA per bar-pair.
// T2 swizzle: LDS linear dest (gload_lds), inverse-permuted global source
// slot, XOR-on-read (rule 21). T4: counted VMCNT(8), never 0 in loop.
__global__ __launch_bounds__(512, 2) void k_gemm256(
    const short* __restrict__ Wt,   // [8192][2048] bf16 (K contig)
    const short* __restrict__ X,    // [2048][2048] bf16 (K contig)
    short* __restrict__ C) {        // [2048][8192] bf16
  __shared__ char lds[2][65536];    // slot: A 32KB | B 32KB
  const int tid = threadIdx.x;
  const int lane = tid & 63, wave = tid >> 6;
  const int wr = wave >> 2, wc = wave & 3;
  const int ln15 = lane & 15, l16 = lane >> 4;
  const int m0 = blockIdx.x * 256, t0 = blockIdx.y * 256;
  const int swz = (ln15 & 7) << 4;               // read-side XOR (bits 4-6)
  const int srow = tid >> 3;                     // staging row 0..63 per call
  const int sslot = ((tid & 7) ^ ((tid >> 3) & 7)) << 4;  // src 16B slot
  const char* Wb = (const char*)Wt;
  const char* Xb = (const char*)X;
  auto STAGE = [&](int kt, int s) {              // 8 gloads/wave per K-tile
#pragma unroll
    for (int c = 0; c < 4; ++c) {
      gload16(Wb + (size_t)(m0 + c * 64 + srow) * 4096 + kt * 128 + sslot,
              &lds[s][c * 8192] + wave * 1024);
      gload16(Xb + (size_t)(t0 + c * 64 + srow) * 4096 + kt * 128 + sslot,
              &lds[s][32768 + c * 8192] + wave * 1024);
    }
  };
  f32x4 acc[8][4];
#pragma unroll
  for (int m = 0; m < 8; ++m)
#pragma unroll
    for (int n = 0; n < 4; ++n) acc[m][n] = (f32x4)0.f;
  const int NT = HD / 64;   // 32 K-tiles
  STAGE(0, 0);
  STAGE(1, 1);
  VMCNT(8);                 // tile0 resident (8 newest = tile1 outstanding)
  SCHED0();
  BAR();
#pragma unroll 2
  for (int kt = 0; kt < NT; ++kt) {
    const int s = kt & 1;
    const char* sA = &lds[s][0];
    const char* sB = &lds[s][32768];
#pragma unroll
    for (int mh = 0; mh < 2; ++mh)
#pragma unroll
      for (int ks = 0; ks < 2; ++ks) {
        const int ka = (ks * 64 + l16 * 16) ^ swz;
        s16x8 a[4], b[4];
#pragma unroll
        for (int f = 0; f < 4; ++f)
          a[f] = *(const s16x8*)(sA + (wr * 128 + mh * 64 + f * 16 + ln15) * 128 + ka);
#pragma unroll
        for (int n = 0; n < 4; ++n)
          b[n] = *(const s16x8*)(sB + (wc * 64 + n * 16 + ln15) * 128 + ka);
        __builtin_amdgcn_s_setprio(1);
#pragma unroll
        for (int f = 0; f < 4; ++f)
#pragma unroll
          for (int n = 0; n < 4; ++n)
            acc[mh * 4 + f][n] = MFMA(a[f], b[n], acc[mh * 4 + f][n]);
        __builtin_amdgcn_s_setprio(0);
      }
    BAR();                           // all waves done reading slot s
    if (kt + 2 < NT) {
      STAGE(kt + 2, s);              // restage freed slot
      VMCNT(8);                      // tile kt+1 resident (kt+2 in flight)
    } else if (kt + 1 < NT) {
      VMCNT(0);                      // tail: drain last tile
    }
    SCHED0();
    BAR();                           // collective: next tile visible
  }
#pragma unroll
  for (int mi = 0; mi < 8; ++mi)
#pragma unroll
    for (int n = 0; n < 4; ++n) {
      const int t = t0 + wc * 64 + n * 16 + ln15;
      const int i = m0 + wr * 128 + mi * 16 + l16 * 4;
      s16x4 o;
#pragma unroll
      for (int r = 0; r < 4; ++r) o[r] = f2bf(acc[mi][n][r]);
      *(s16x4*)(C + (size_t)t * ID + i) = o;
    }
}

// ---------------- K3b: fused gelu(gate)*up elementwise -------------------
__global__ __launch_bounds__(256) void k_gelumul(
    const short* __restrict__ g, const short* __restrict__ u,
    short* __restrict__ o) {
  const size_t idx = ((size_t)blockIdx.x * 256 + threadIdx.x) * 8;
  s16x8 gv = *(const s16x8*)(g + idx);
  s16x8 uv = *(const s16x8*)(u + idx);
  s16x8 ov;
#pragma unroll
  for (int j = 0; j < 8; ++j)
    ov[j] = f2bf(gelu_tanh(bf2f(gv[j])) * bf2f(uv[j]));
  *(s16x8*)(o + idx) = ov;
}

// ------- K4: dense down GEMM, split-K x4 (128x128 tile, 1024 blocks) -----
__global__ __launch_bounds__(256) void k_dense_down(
    const short* __restrict__ wdT,   // [H][I]
    const short* __restrict__ act,   // [T][I]
    float* __restrict__ dparts) {    // [KSPLIT][T][H]
  __shared__ short sW[128 * 32];
  __shared__ short sX[128 * 32];
  const int tid = threadIdx.x;
  const int n0 = blockIdx.x * 128, t0 = blockIdx.y * 128;
  const int kbase = blockIdx.z * (ID / KSPLIT);
  const int lane = tid & 63, wave = tid >> 6;
  const int wr = wave >> 1, wc = wave & 1;
  const int ln15 = lane & 15, k8 = (lane >> 4) * 8;
  const int srow = tid >> 2, skc = (tid & 3) * 8;
  const short* gW0 = wdT + (size_t)(n0 + srow) * ID + kbase + skc;
  const short* gW1 = wdT + (size_t)(n0 + 64 + srow) * ID + kbase + skc;
  const short* gX0 = act + (size_t)(t0 + srow) * ID + kbase + skc;
  const short* gX1 = act + (size_t)(t0 + 64 + srow) * ID + kbase + skc;
  char* lW = (char*)sW + wave * 1024;
  char* lX = (char*)sX + wave * 1024;
  f32x4 acc[4][4];
#pragma unroll
  for (int m = 0; m < 4; ++m)
#pragma unroll
    for (int n = 0; n < 4; ++n) acc[m][n] = (f32x4)0.f;
  for (int kt = 0; kt < ID / KSPLIT / 32; ++kt) {
    const int ko = kt * 32;
    __syncthreads();
    gload16(gW0 + ko, lW);
    gload16(gW1 + ko, lW + 4096);
    gload16(gX0 + ko, lX);
    gload16(gX1 + ko, lX + 4096);
    __syncthreads();
    s16x8 a[4], b[4];
#pragma unroll
    for (int m = 0; m < 4; ++m)
      a[m] = *(const s16x8*)(sW + (wr * 64 + m * 16 + ln15) * 32 + k8);
#pragma unroll
    for (int n = 0; n < 4; ++n)
      b[n] = *(const s16x8*)(sX + (wc * 64 + n * 16 + ln15) * 32 + k8);
#pragma unroll
    for (int m = 0; m < 4; ++m)
#pragma unroll
      for (int n = 0; n < 4; ++n) acc[m][n] = MFMA(a[m], b[n], acc[m][n]);
  }
  float* dst = dparts + (size_t)blockIdx.z * TOK * HD;
#pragma unroll
  for (int n = 0; n < 4; ++n) {
    const int t = t0 + wc * 64 + n * 16 + ln15;
#pragma unroll
    for (int m = 0; m < 4; ++m) {
      const int h = n0 + wr * 64 + m * 16 + (lane >> 4) * 4;
      *(f32x4*)(dst + (size_t)t * HD + h) = acc[m][n];
    }
  }
}

// ---------------- K5: expert gate+up GEMM (gathered tokens) --------------
__global__ __launch_bounds__(256) void k_exp_gateup(
    const short* __restrict__ wegT, const short* __restrict__ weuT,  // [E][MI][H]
    const short* __restrict__ rms2,                                   // [T][H]
    const int* __restrict__ cnt, const int* __restrict__ tokl,
    short* __restrict__ acte) {                                       // [E][T][MI]
  const int e = blockIdx.z;
  const int cn = cnt[e];
  const int t0 = blockIdx.y * 128;
  if (t0 >= cn) return;
  const int n0 = blockIdx.x * 64;
  __shared__ short sW[128 * 32];
  __shared__ short sX[128 * 32];
  const int tid = threadIdx.x;
  const int lane = tid & 63, wave = tid >> 6;
  const int ln15 = lane & 15, k8 = (lane >> 4) * 8;
  const int nsub = (wave & 1) * 32, tsub = (wave >> 1) * 64;
  const int srow = tid >> 2, skc = (tid & 3) * 8;
  const int* tl = tokl + e * TOK;
  int r0 = t0 + srow, r1 = t0 + 64 + srow;
  int tk0 = tl[r0 < cn ? r0 : cn - 1];
  int tk1 = tl[r1 < cn ? r1 : cn - 1];
  const short* gW0 = wegT + (size_t)e * MID * HD + (size_t)(n0 + srow) * HD + skc;
  const short* gW1 = weuT + (size_t)e * MID * HD + (size_t)(n0 + srow) * HD + skc;
  const short* gX0 = rms2 + (size_t)tk0 * HD + skc;
  const short* gX1 = rms2 + (size_t)tk1 * HD + skc;
  char* lW = (char*)sW + wave * 1024;
  char* lX = (char*)sX + wave * 1024;
  f32x4 accg[2][4], accu[2][4];
#pragma unroll
  for (int m = 0; m < 2; ++m)
#pragma unroll
    for (int n = 0; n < 4; ++n) { accg[m][n] = (f32x4)0.f; accu[m][n] = (f32x4)0.f; }
  for (int kt = 0; kt < HD / 32; ++kt) {
    const int ko = kt * 32;
    __syncthreads();
    gload16(gW0 + ko, lW);
    gload16(gW1 + ko, lW + 4096);
    gload16(gX0 + ko, lX);
    gload16(gX1 + ko, lX + 4096);
    __syncthreads();
    s16x8 ag[2], au[2], bx[4];
#pragma unroll
    for (int m = 0; m < 2; ++m) {
      ag[m] = *(const s16x8*)(sW + (nsub + m * 16 + ln15) * 32 + k8);
      au[m] = *(const s16x8*)(sW + (64 + nsub + m * 16 + ln15) * 32 + k8);
    }
#pragma unroll
    for (int n = 0; n < 4; ++n)
      bx[n] = *(const s16x8*)(sX + (tsub + n * 16 + ln15) * 32 + k8);
#pragma unroll
    for (int m = 0; m < 2; ++m)
#pragma unroll
      for (int n = 0; n < 4; ++n) {
        accg[m][n] = MFMA(ag[m], bx[n], accg[m][n]);
        accu[m][n] = MFMA(au[m], bx[n], accu[m][n]);
      }
  }
#pragma unroll
  for (int m = 0; m < 2; ++m)
#pragma unroll
    for (int n = 0; n < 4; ++n) {
      const int r = t0 + tsub + n * 16 + ln15;
      if (r < cn) {
        const int ib = n0 + nsub + m * 16 + (lane >> 4) * 4;
        s16x4 o;
#pragma unroll
        for (int q = 0; q < 4; ++q)
          o[q] = f2bf(gelu_tanh(accg[m][n][q]) * accu[m][n][q]);
        *(s16x4*)(acte + (size_t)e * TOK * MID + (size_t)r * MID + ib) = o;
      }
    }
}

// ---------------- K6: expert down GEMM (128x128) + weighted scatter ------
__global__ __launch_bounds__(256) void k_exp_down(
    const short* __restrict__ wedT,   // [E][H][MI]
    const short* __restrict__ acte,   // [E][T][MI]
    const int* __restrict__ cnt, const int* __restrict__ tokl,
    const float* __restrict__ wgtl, const int* __restrict__ slotl,
    float* __restrict__ moep) {       // [2][T][H]
  const int e = blockIdx.z;
  const int cn = cnt[e];
  const int t0 = blockIdx.y * 128;
  if (t0 >= cn) return;
  const int n0 = blockIdx.x * 128;
  __shared__ short sW[128 * 32];
  __shared__ short sX[128 * 32];
  const int tid = threadIdx.x;
  const int lane = tid & 63, wave = tid >> 6;
  const int wr = wave >> 1, wc = wave & 1;
  const int ln15 = lane & 15, k8 = (lane >> 4) * 8;
  const int srow = tid >> 2, skc = (tid & 3) * 8;
  const short* wb = wedT + (size_t)e * HD * MID;
  const short* gW0 = wb + (size_t)(n0 + srow) * MID + skc;
  const short* gW1 = wb + (size_t)(n0 + 64 + srow) * MID + skc;
  const short* ab = acte + (size_t)e * TOK * MID;
  const short* gX0 = ab + (size_t)(t0 + srow) * MID + skc;
  const short* gX1 = ab + (size_t)(t0 + 64 + srow) * MID + skc;
  char* lW = (char*)sW + wave * 1024;
  char* lX = (char*)sX + wave * 1024;
  f32x4 acc[4][4];
#pragma unroll
  for (int m = 0; m < 4; ++m)
#pragma unroll
    for (int n = 0; n < 4; ++n) acc[m][n] = (f32x4)0.f;
  for (int kt = 0; kt < MID / 32; ++kt) {
    const int ko = kt * 32;
    __syncthreads();
    gload16(gW0 + ko, lW);
    gload16(gW1 + ko, lW + 4096);
    gload16(gX0 + ko, lX);
    gload16(gX1 + ko, lX + 4096);
    __syncthreads();
    s16x8 a[4], b[4];
#pragma unroll
    for (int m = 0; m < 4; ++m)
      a[m] = *(const s16x8*)(sW + (wr * 64 + m * 16 + ln15) * 32 + k8);
#pragma unroll
    for (int n = 0; n < 4; ++n)
      b[n] = *(const s16x8*)(sX + (wc * 64 + n * 16 + ln15) * 32 + k8);
#pragma unroll
    for (int m = 0; m < 4; ++m)
#pragma unroll
      for (int n = 0; n < 4; ++n) acc[m][n] = MFMA(a[m], b[n], acc[m][n]);
  }
#pragma unroll
  for (int n = 0; n < 4; ++n) {
    const int r = t0 + wc * 64 + n * 16 + ln15;
    if (r < cn) {
      const int tk = tokl[e * TOK + r];
      const float wf = wgtl[e * TOK + r];
      const int sl = slotl[e * TOK + r];
      float* dst = moep + (size_t)sl * TOK * HD + (size_t)tk * HD;
#pragma unroll
      for (int m = 0; m < 4; ++m) {
        const int h = n0 + wr * 64 + m * 16 + (lane >> 4) * 4;
        f32x4 v = acc[m][n] * wf;
        *(f32x4*)(dst + h) = v;
      }
    }
  }
}

// ---------------- K7: final triple RMSNorm fusion ------------------------
__global__ __launch_bounds__(256) void k_final(
    const float* __restrict__ dparts, const float* __restrict__ moep,
    const float* __restrict__ rno1, const float* __restrict__ rno2,
    const float* __restrict__ rnof, float* __restrict__ out) {
  const int t = blockIdx.x, tid = threadIdx.x;
  const size_t base = (size_t)t * HD;
  f32x4 dv[2], mv[2];
  float ssd = 0.f, ssm = 0.f;
#pragma unroll
  for (int i = 0; i < 2; ++i) {
    const int h = tid * 4 + i * 1024;
    dv[i] = (f32x4)0.f;
#pragma unroll
    for (int z = 0; z < KSPLIT; ++z)
      dv[i] += *(const f32x4*)(dparts + (size_t)z * TOK * HD + base + h);
    f32x4 a = *(const f32x4*)(moep + base + h);
    f32x4 b = *(const f32x4*)(moep + (size_t)TOK * HD + base + h);
    mv[i] = a + b;
#pragma unroll
    for (int j = 0; j < 4; ++j) { ssd += dv[i][j] * dv[i][j]; ssm += mv[i][j] * mv[i][j]; }
  }
  __shared__ float sr[8];
#pragma unroll
  for (int off = 32; off; off >>= 1) {
    ssd += __shfl_down(ssd, off, 64);
    ssm += __shfl_down(ssm, off, 64);
  }
  if ((tid & 63) == 0) { sr[tid >> 6] = ssd; sr[4 + (tid >> 6)] = ssm; }
  __syncthreads();
  const float invd = rsqrtf((sr[0] + sr[1] + sr[2] + sr[3]) * (1.0f / HD) + EPSF);
  const float invm = rsqrtf((sr[4] + sr[5] + sr[6] + sr[7]) * (1.0f / HD) + EPSF);
  f32x4 y[2];
  float ssy = 0.f;
#pragma unroll
  for (int i = 0; i < 2; ++i) {
    const int h = tid * 4 + i * 1024;
    f32x4 w1 = *(const f32x4*)(rno1 + h);
    f32x4 w2 = *(const f32x4*)(rno2 + h);
#pragma unroll
    for (int j = 0; j < 4; ++j) {
      y[i][j] = dv[i][j] * invd * w1[j] + mv[i][j] * invm * w2[j];
      ssy += y[i][j] * y[i][j];
    }
  }
  __syncthreads();
#pragma unroll
  for (int off = 32; off; off >>= 1) ssy += __shfl_down(ssy, off, 64);
  if ((tid & 63) == 0) sr[tid >> 6] = ssy;
  __syncthreads();
  const float invy = rsqrtf((sr[0] + sr[1] + sr[2] + sr[3]) * (1.0f / HD) + EPSF);
#pragma unroll
  for (int i = 0; i < 2; ++i) {
    const int h = tid * 4 + i * 1024;
    f32x4 w = *(const f32x4*)(rnof + h);
    f32x4 o;
#pragma unroll
    for (int j = 0; j < 4; ++j) o[j] = y[i][j] * invy * w[j];
    *(f32x4*)(out + base + h) = o;
  }
}

// ---------------- launcher ----------------------------------------------
extern "C" void kernel_launch(void* const* d_in, const int* in_sizes, int n_in,
                              void* d_out, int out_size, void* d_ws, size_t ws_size,
                              hipStream_t stream) {
  (void)in_sizes; (void)n_in; (void)out_size;
  const float* x    = (const float*)d_in[0];
  const float* rnp1 = (const float*)d_in[1];
  const float* rnp2 = (const float*)d_in[2];
  const float* rno1 = (const float*)d_in[3];
  const float* rno2 = (const float*)d_in[4];
  const float* rnof = (const float*)d_in[5];
  const float* wg   = (const float*)d_in[6];
  const float* wu   = (const float*)d_in[7];
  const float* wd   = (const float*)d_in[8];
  const float* rw   = (const float*)d_in[9];
  const float* rsc  = (const float*)d_in[10];
  const float* pes  = (const float*)d_in[11];
  const float* weg  = (const float*)d_in[12];
  const float* weu  = (const float*)d_in[13];
  const float* wed  = (const float*)d_in[14];
  float* out = (float*)d_out;

  char* ws = (char*)d_ws;
  size_t off = 0;
  auto alloc = [&](size_t bytes) -> void* {
    void* p = ws + off;
    off += (bytes + 255) & ~(size_t)255;
    return p;
  };
  const size_t IH  = (size_t)ID * HD;
  const size_t EMH = (size_t)NE * MID * HD;
  short* wgT   = (short*)alloc(IH * 2);   // wgT+wuT contiguous (67 MB),
  short* wuT   = (short*)alloc(IH * 2);   // reused as dparts after gelumul
  short* wdT   = (short*)alloc(IH * 2);
  short* wegT  = (short*)alloc(EMH * 2);
  short* weuT  = (short*)alloc(EMH * 2);
  short* wedT  = (short*)alloc(EMH * 2);
  short* rms1  = (short*)alloc((size_t)TOK * HD * 2);
  short* rms2  = (short*)alloc((size_t)TOK * HD * 2);
  short* actb  = (short*)alloc((size_t)TOK * ID * 2);
  short* acte  = (short*)alloc((size_t)NE * TOK * MID * 2);   // 33.5 MB
  float* moep  = (float*)alloc((size_t)2 * TOK * HD * 4);     // 33.5 MB
  int*   cnt   = (int*)alloc(NE * 4);
  int*   tokl  = (int*)alloc((size_t)NE * TOK * 4);
  float* wgtl  = (float*)alloc((size_t)NE * TOK * 4);
  int*   slotl = (int*)alloc((size_t)NE * TOK * 4);
  if (off > ws_size) return;  // workspace too small: bail cleanly
  // split-K partials alias wgT/wuT (dead after up-GEMM; exactly 67,108,864 B)
  float* dparts = (float*)wgT;
  // gate/up GEMM outputs alias acte / moep (both dead in this window;
  // each region is exactly TOK*ID*2 = 33,554,432 B)
  short* gbuf = acte;
  short* ubuf = (short*)moep;

  hipMemsetAsync(cnt, 0, NE * 4, stream);
  k_rms_router<<<TOK, 256, 0, stream>>>(x, rnp1, rnp2, rsc, rw, pes,
                                        rms1, rms2, cnt, tokl, wgtl, slotl);
  k_transpose<<<dim3(ID / 64, HD / 64, 1), 256, 0, stream>>>(wg, wgT, HD, ID);
  k_transpose<<<dim3(ID / 64, HD / 64, 1), 256, 0, stream>>>(wu, wuT, HD, ID);
  k_transpose<<<dim3(HD / 64, ID / 64, 1), 256, 0, stream>>>(wd, wdT, ID, HD);
  k_transpose<<<dim3(MID / 64, HD / 64, NE), 256, 0, stream>>>(weg, wegT, HD, MID);
  k_transpose<<<dim3(MID / 64, HD / 64, NE), 256, 0, stream>>>(weu, weuT, HD, MID);
  k_transpose<<<dim3(HD / 64, MID / 64, NE), 256, 0, stream>>>(wed, wedT, MID, HD);
  k_gemm256<<<dim3(ID / 256, TOK / 256), 512, 0, stream>>>(wgT, rms1, gbuf);
  k_gemm256<<<dim3(ID / 256, TOK / 256), 512, 0, stream>>>(wuT, rms1, ubuf);
  k_gelumul<<<(TOK * (size_t)ID) / (256 * 8), 256, 0, stream>>>(gbuf, ubuf, actb);
  k_dense_down<<<dim3(HD / 128, TOK / 128, KSPLIT), 256, 0, stream>>>(wdT, actb, dparts);
  k_exp_gateup<<<dim3(MID / 64, TOK / 128, NE), 256, 0, stream>>>(wegT, weuT, rms2,
                                                                  cnt, tokl, acte);
  k_exp_down<<<dim3(HD / 128, TOK / 128, NE), 256, 0, stream>>>(wedT, acte, cnt, tokl,
                                                                wgtl, slotl, moep);
  k_final<<<TOK, 256, 0, stream>>>(dparts, moep, rno1, rno2, rnof, out);
}

// Round 6
// 551.533 us; speedup vs baseline: 1.2820x; 1.1127x over previous
//
#include <hip/hip_runtime.h>
#include <stdint.h>

#define TOK 2048   // B*S tokens
#define HD  2048   // hidden
#define ID  8192   // dense intermediate
#define ID2 16384  // merged gate|up output row stride
#define MID 1024   // moe intermediate
#define NE  8      // experts
#define KSPLIT 4   // split-K ways for dense down GEMM

typedef __attribute__((ext_vector_type(8))) short s16x8;
typedef __attribute__((ext_vector_type(4))) short s16x4;
typedef __attribute__((ext_vector_type(4))) float f32x4;

constexpr float EPSF  = 1e-6f;
constexpr float ROOTF = 0.02209708691207961f;  // 2048^-0.5

#define MFMA(a, b, c) __builtin_amdgcn_mfma_f32_16x16x32_bf16(a, b, c, 0, 0, 0)
#define BAR() __builtin_amdgcn_s_barrier()
#define SCHED0() __builtin_amdgcn_sched_barrier(0)
#define VMCNT(n) asm volatile("s_waitcnt vmcnt(" #n ")" ::: "memory")

// async global->LDS, 16 B per lane. LDS dest must be wave-uniform base;
// HW writes base + lane*16. Global src is per-lane.
__device__ __forceinline__ void gload16(const void* g, void* l) {
  __builtin_amdgcn_global_load_lds(
      (const __attribute__((address_space(1))) void*)g,
      (__attribute__((address_space(3))) void*)l, 16, 0, 0);
}

__device__ __forceinline__ short f2bf(float f) {
  union { float f; uint32_t u; } v; v.f = f;
  uint32_t r = v.u + 0x7fffu + ((v.u >> 16) & 1u);   // RNE
  return (short)(r >> 16);
}

__device__ __forceinline__ float bf2f(short s) {
  union { uint32_t u; float f; } v; v.u = ((uint32_t)(uint16_t)s) << 16;
  return v.f;
}

__device__ __forceinline__ float gelu_tanh(float x) {
  float x3 = x * x * x;
  float u = 0.7978845608028654f * (x + 0.044715f * x3);
  return 0.5f * x * (1.0f + tanhf(u));
}

// ---------------- K1: RMSNorms (pre1/pre2) + router + top-2 gather -------
__global__ __launch_bounds__(256) void k_rms_router(
    const float* __restrict__ x, const float* __restrict__ rnp1,
    const float* __restrict__ rnp2, const float* __restrict__ rsc,
    const float* __restrict__ rw, const float* __restrict__ pes,
    short* __restrict__ rms1, short* __restrict__ rms2,
    int* __restrict__ cnt, int* __restrict__ tokl,
    float* __restrict__ wgtl, int* __restrict__ slotl) {
  const int t = blockIdx.x, tid = threadIdx.x;
  const size_t base = (size_t)t * HD;
  f32x4 v[2];
  float ss = 0.f;
#pragma unroll
  for (int i = 0; i < 2; ++i) {
    v[i] = *(const f32x4*)(x + base + tid * 4 + i * 1024);
#pragma unroll
    for (int j = 0; j < 4; ++j) ss += v[i][j] * v[i][j];
  }
  __shared__ float sr[4];
  __shared__ float sl[32];
#pragma unroll
  for (int off = 32; off; off >>= 1) ss += __shfl_down(ss, off, 64);
  if ((tid & 63) == 0) sr[tid >> 6] = ss;
  __syncthreads();
  const float inv = rsqrtf((sr[0] + sr[1] + sr[2] + sr[3]) * (1.0f / HD) + EPSF);
  float p[8] = {0, 0, 0, 0, 0, 0, 0, 0};
#pragma unroll
  for (int i = 0; i < 2; ++i) {
    const int h = tid * 4 + i * 1024;
    f32x4 w1 = *(const f32x4*)(rnp1 + h);
    f32x4 w2 = *(const f32x4*)(rnp2 + h);
    f32x4 sc = *(const f32x4*)(rsc + h);
    s16x4 o1, o2;
#pragma unroll
    for (int j = 0; j < 4; ++j) {
      float xn = v[i][j] * inv;
      o1[j] = f2bf(xn * w1[j]);
      o2[j] = f2bf(xn * w2[j]);
      float xq = xn * sc[j] * ROOTF;
      const float* rr = rw + (size_t)(h + j) * NE;
      f32x4 ra = *(const f32x4*)rr;
      f32x4 rb = *(const f32x4*)(rr + 4);
      p[0] += xq * ra[0]; p[1] += xq * ra[1]; p[2] += xq * ra[2]; p[3] += xq * ra[3];
      p[4] += xq * rb[0]; p[5] += xq * rb[1]; p[6] += xq * rb[2]; p[7] += xq * rb[3];
    }
    *(s16x4*)(rms1 + base + h) = o1;
    *(s16x4*)(rms2 + base + h) = o2;
  }
#pragma unroll
  for (int e = 0; e < 8; ++e)
#pragma unroll
    for (int off = 32; off; off >>= 1) p[e] += __shfl_down(p[e], off, 64);
  if ((tid & 63) == 0) {
#pragma unroll
    for (int e = 0; e < 8; ++e) sl[(tid >> 6) * 8 + e] = p[e];
  }
  __syncthreads();
  if (tid == 0) {
    float l[8];
#pragma unroll
    for (int e = 0; e < 8; ++e) l[e] = sl[e] + sl[8 + e] + sl[16 + e] + sl[24 + e];
    int i1 = 0;
#pragma unroll
    for (int e = 1; e < 8; ++e) if (l[e] > l[i1]) i1 = e;
    int i2 = (i1 == 0) ? 1 : 0;
#pragma unroll
    for (int e = 0; e < 8; ++e) if (e != i1 && l[e] > l[i2]) i2 = e;
    float p2 = expf(l[i2] - l[i1]);     // p1 = 1
    float s = 1.0f + p2;
    float w1 = (1.0f / s) * pes[i1];
    float w2 = (p2 / s) * pes[i2];
    int q1 = atomicAdd(&cnt[i1], 1);
    tokl[i1 * TOK + q1] = t; wgtl[i1 * TOK + q1] = w1; slotl[i1 * TOK + q1] = 0;
    int q2 = atomicAdd(&cnt[i2], 1);
    tokl[i2 * TOK + q2] = t; wgtl[i2 * TOK + q2] = w2; slotl[i2 * TOK + q2] = 1;
  }
}

// ---------------- K2: fp32 (R,C) -> bf16 (C,R) transpose-convert ---------
__global__ __launch_bounds__(256) void k_transpose(
    const float* __restrict__ in, short* __restrict__ out, int R, int C) {
  __shared__ float tile[64 * 65];
  const int tid = threadIdx.x;
  const int c0 = blockIdx.x * 64, r0 = blockIdx.y * 64;
  const size_t bo = (size_t)blockIdx.z * R * C;
#pragma unroll
  for (int i = 0; i < 4; ++i) {
    int idx = tid + 256 * i;
    int r = idx >> 4, c4 = idx & 15;
    f32x4 f = *(const f32x4*)(in + bo + (size_t)(r0 + r) * C + c0 + c4 * 4);
#pragma unroll
    for (int j = 0; j < 4; ++j) tile[(c4 * 4 + j) * 65 + r] = f[j];
  }
  __syncthreads();
#pragma unroll
  for (int i = 0; i < 2; ++i) {
    int ch = tid + 256 * i;
    int c = ch >> 3, rs = ch & 7;
    s16x8 o;
#pragma unroll
    for (int q = 0; q < 8; ++q) o[q] = f2bf(tile[c * 65 + rs * 8 + q]);
    *(s16x8*)(out + bo + (size_t)(c0 + c) * R + r0 + rs * 8) = o;
  }
}

// ---------------- K3: 256x256 BK=64 deep-pipelined GEMM (bf16 out) -------
// C[t][m] = X[t][k] * W[m][k]^T, C row stride ID2 (merged gate|up).
// 8 waves (2M x 4N), per-wave 128x64 out, acc[8][4], 64 MFMA per bar-pair.
// T2 swizzle: LDS linear dest (gload_lds), inverse-permuted global source
// slot, XOR-on-read (rule 21). T4: counted VMCNT(8), never 0 in loop.
__global__ __launch_bounds__(512, 2) void k_gemm256(
    const short* __restrict__ Wt,   // [16384][2048] bf16 (K contig)
    const short* __restrict__ X,    // [2048][2048] bf16 (K contig)
    short* __restrict__ C) {        // [2048][ID2] bf16
  __shared__ char lds[2][65536];    // slot: A 32KB | B 32KB
  const int tid = threadIdx.x;
  const int lane = tid & 63, wave = tid >> 6;
  const int wr = wave >> 2, wc = wave & 3;
  const int ln15 = lane & 15, l16 = lane >> 4;
  const int m0 = blockIdx.x * 256, t0 = blockIdx.y * 256;
  const int swz = (ln15 & 7) << 4;               // read-side XOR (bits 4-6)
  const int srow = tid >> 3;                     // staging row 0..63 per call
  const int sslot = ((tid & 7) ^ ((tid >> 3) & 7)) << 4;  // src 16B slot
  const char* Wb = (const char*)Wt;
  const char* Xb = (const char*)X;
  auto STAGE = [&](int kt, int s) {              // 8 gloads/wave per K-tile
#pragma unroll
    for (int c = 0; c < 4; ++c) {
      gload16(Wb + (size_t)(m0 + c * 64 + srow) * 4096 + kt * 128 + sslot,
              &lds[s][c * 8192] + wave * 1024);
      gload16(Xb + (size_t)(t0 + c * 64 + srow) * 4096 + kt * 128 + sslot,
              &lds[s][32768 + c * 8192] + wave * 1024);
    }
  };
  f32x4 acc[8][4];
#pragma unroll
  for (int m = 0; m < 8; ++m)
#pragma unroll
    for (int n = 0; n < 4; ++n) acc[m][n] = (f32x4)0.f;
  const int NT = HD / 64;   // 32 K-tiles
  STAGE(0, 0);
  STAGE(1, 1);
  VMCNT(8);                 // tile0 resident (8 newest = tile1 outstanding)
  SCHED0();
  BAR();
#pragma unroll 2
  for (int kt = 0; kt < NT; ++kt) {
    const int s = kt & 1;
    const char* sA = &lds[s][0];
    const char* sB = &lds[s][32768];
#pragma unroll
    for (int mh = 0; mh < 2; ++mh)
#pragma unroll
      for (int ks = 0; ks < 2; ++ks) {
        const int ka = (ks * 64 + l16 * 16) ^ swz;
        s16x8 a[4], b[4];
#pragma unroll
        for (int f = 0; f < 4; ++f)
          a[f] = *(const s16x8*)(sA + (wr * 128 + mh * 64 + f * 16 + ln15) * 128 + ka);
#pragma unroll
        for (int n = 0; n < 4; ++n)
          b[n] = *(const s16x8*)(sB + (wc * 64 + n * 16 + ln15) * 128 + ka);
        __builtin_amdgcn_s_setprio(1);
#pragma unroll
        for (int f = 0; f < 4; ++f)
#pragma unroll
          for (int n = 0; n < 4; ++n)
            acc[mh * 4 + f][n] = MFMA(a[f], b[n], acc[mh * 4 + f][n]);
        __builtin_amdgcn_s_setprio(0);
      }
    BAR();                           // all waves done reading slot s
    if (kt + 2 < NT) {
      STAGE(kt + 2, s);              // restage freed slot
      VMCNT(8);                      // tile kt+1 resident (kt+2 in flight)
    } else if (kt + 1 < NT) {
      VMCNT(0);                      // tail: drain last tile
    }
    SCHED0();
    BAR();                           // collective: next tile visible
  }
#pragma unroll
  for (int mi = 0; mi < 8; ++mi)
#pragma unroll
    for (int n = 0; n < 4; ++n) {
      const int t = t0 + wc * 64 + n * 16 + ln15;
      const int i = m0 + wr * 128 + mi * 16 + l16 * 4;
      s16x4 o;
#pragma unroll
      for (int r = 0; r < 4; ++r) o[r] = f2bf(acc[mi][n][r]);
      *(s16x4*)(C + (size_t)t * ID2 + i) = o;
    }
}

// ------- K4: dense down GEMM, 256x256 pipeline, split-K x4, fp32 out -----
// Same staging/swizzle/vmcnt schedule as k_gemm256 (validated round 5);
// A/B row stride = ID elems, per-block K window = ID/KSPLIT = 2048 (NT=32).
__global__ __launch_bounds__(512, 2) void k_dd256(
    const short* __restrict__ Wd,   // [2048][8192] bf16 (K contig)
    const short* __restrict__ X,    // [2048][8192] bf16 (K contig)
    float* __restrict__ dparts) {   // [KSPLIT][2048][2048] fp32
  __shared__ char lds[2][65536];
  const int tid = threadIdx.x;
  const int lane = tid & 63, wave = tid >> 6;
  const int wr = wave >> 2, wc = wave & 3;
  const int ln15 = lane & 15, l16 = lane >> 4;
  const int m0 = blockIdx.x * 256, t0 = blockIdx.y * 256;
  const size_t kB = (size_t)blockIdx.z * 4096;   // K window byte offset
  const int swz = (ln15 & 7) << 4;
  const int srow = tid >> 3;
  const int sslot = ((tid & 7) ^ ((tid >> 3) & 7)) << 4;
  const char* Wb = (const char*)Wd;
  const char* Xb = (const char*)X;
  auto STAGE = [&](int kt, int s) {
#pragma unroll
    for (int c = 0; c < 4; ++c) {
      gload16(Wb + (size_t)(m0 + c * 64 + srow) * 16384 + kB + kt * 128 + sslot,
              &lds[s][c * 8192] + wave * 1024);
      gload16(Xb + (size_t)(t0 + c * 64 + srow) * 16384 + kB + kt * 128 + sslot,
              &lds[s][32768 + c * 8192] + wave * 1024);
    }
  };
  f32x4 acc[8][4];
#pragma unroll
  for (int m = 0; m < 8; ++m)
#pragma unroll
    for (int n = 0; n < 4; ++n) acc[m][n] = (f32x4)0.f;
  const int NT = (ID / KSPLIT) / 64;   // 32 K-tiles
  STAGE(0, 0);
  STAGE(1, 1);
  VMCNT(8);
  SCHED0();
  BAR();
#pragma unroll 2
  for (int kt = 0; kt < NT; ++kt) {
    const int s = kt & 1;
    const char* sA = &lds[s][0];
    const char* sB = &lds[s][32768];
#pragma unroll
    for (int mh = 0; mh < 2; ++mh)
#pragma unroll
      for (int ks = 0; ks < 2; ++ks) {
        const int ka = (ks * 64 + l16 * 16) ^ swz;
        s16x8 a[4], b[4];
#pragma unroll
        for (int f = 0; f < 4; ++f)
          a[f] = *(const s16x8*)(sA + (wr * 128 + mh * 64 + f * 16 + ln15) * 128 + ka);
#pragma unroll
        for (int n = 0; n < 4; ++n)
          b[n] = *(const s16x8*)(sB + (wc * 64 + n * 16 + ln15) * 128 + ka);
        __builtin_amdgcn_s_setprio(1);
#pragma unroll
        for (int f = 0; f < 4; ++f)
#pragma unroll
          for (int n = 0; n < 4; ++n)
            acc[mh * 4 + f][n] = MFMA(a[f], b[n], acc[mh * 4 + f][n]);
        __builtin_amdgcn_s_setprio(0);
      }
    BAR();
    if (kt + 2 < NT) {
      STAGE(kt + 2, s);
      VMCNT(8);
    } else if (kt + 1 < NT) {
      VMCNT(0);
    }
    SCHED0();
    BAR();
  }
  float* dst = dparts + (size_t)blockIdx.z * TOK * HD;
#pragma unroll
  for (int mi = 0; mi < 8; ++mi)
#pragma unroll
    for (int n = 0; n < 4; ++n) {
      const int t = t0 + wc * 64 + n * 16 + ln15;
      const int h = m0 + wr * 128 + mi * 16 + l16 * 4;
      *(f32x4*)(dst + (size_t)t * HD + h) = acc[mi][n];
    }
}

// ---------------- K3b: fused gelu(gate)*up elementwise -------------------
// cbuf rows are [gate(0..8191) | up(8192..16383)].
__global__ __launch_bounds__(256) void k_gelumul(
    const short* __restrict__ cbuf, short* __restrict__ o) {
  const int flat = blockIdx.x * 256 + threadIdx.x;
  const int t = flat >> 10;                // ID/8 = 1024 chunks per row
  const int i8 = (flat & 1023) * 8;
  const short* g = cbuf + (size_t)t * ID2 + i8;
  s16x8 gv = *(const s16x8*)g;
  s16x8 uv = *(const s16x8*)(g + ID);
  s16x8 ov;
#pragma unroll
  for (int j = 0; j < 8; ++j)
    ov[j] = f2bf(gelu_tanh(bf2f(gv[j])) * bf2f(uv[j]));
  *(s16x8*)(o + (size_t)t * ID + i8) = ov;
}

// ---------------- K5: expert gate+up GEMM (gathered tokens) --------------
__global__ __launch_bounds__(256) void k_exp_gateup(
    const short* __restrict__ wegT, const short* __restrict__ weuT,  // [E][MI][H]
    const short* __restrict__ rms2,                                   // [T][H]
    const int* __restrict__ cnt, const int* __restrict__ tokl,
    short* __restrict__ acte) {                                       // [E][T][MI]
  const int e = blockIdx.z;
  const int cn = cnt[e];
  const int t0 = blockIdx.y * 128;
  if (t0 >= cn) return;
  const int n0 = blockIdx.x * 64;
  __shared__ short sW[128 * 32];
  __shared__ short sX[128 * 32];
  const int tid = threadIdx.x;
  const int lane = tid & 63, wave = tid >> 6;
  const int ln15 = lane & 15, k8 = (lane >> 4) * 8;
  const int nsub = (wave & 1) * 32, tsub = (wave >> 1) * 64;
  const int srow = tid >> 2, skc = (tid & 3) * 8;
  const int* tl = tokl + e * TOK;
  int r0 = t0 + srow, r1 = t0 + 64 + srow;
  int tk0 = tl[r0 < cn ? r0 : cn - 1];
  int tk1 = tl[r1 < cn ? r1 : cn - 1];
  const short* gW0 = wegT + (size_t)e * MID * HD + (size_t)(n0 + srow) * HD + skc;
  const short* gW1 = weuT + (size_t)e * MID * HD + (size_t)(n0 + srow) * HD + skc;
  const short* gX0 = rms2 + (size_t)tk0 * HD + skc;
  const short* gX1 = rms2 + (size_t)tk1 * HD + skc;
  char* lW = (char*)sW + wave * 1024;
  char* lX = (char*)sX + wave * 1024;
  f32x4 accg[2][4], accu[2][4];
#pragma unroll
  for (int m = 0; m < 2; ++m)
#pragma unroll
    for (int n = 0; n < 4; ++n) { accg[m][n] = (f32x4)0.f; accu[m][n] = (f32x4)0.f; }
  for (int kt = 0; kt < HD / 32; ++kt) {
    const int ko = kt * 32;
    __syncthreads();
    gload16(gW0 + ko, lW);
    gload16(gW1 + ko, lW + 4096);
    gload16(gX0 + ko, lX);
    gload16(gX1 + ko, lX + 4096);
    __syncthreads();
    s16x8 ag[2], au[2], bx[4];
#pragma unroll
    for (int m = 0; m < 2; ++m) {
      ag[m] = *(const s16x8*)(sW + (nsub + m * 16 + ln15) * 32 + k8);
      au[m] = *(const s16x8*)(sW + (64 + nsub + m * 16 + ln15) * 32 + k8);
    }
#pragma unroll
    for (int n = 0; n < 4; ++n)
      bx[n] = *(const s16x8*)(sX + (tsub + n * 16 + ln15) * 32 + k8);
#pragma unroll
    for (int m = 0; m < 2; ++m)
#pragma unroll
      for (int n = 0; n < 4; ++n) {
        accg[m][n] = MFMA(ag[m], bx[n], accg[m][n]);
        accu[m][n] = MFMA(au[m], bx[n], accu[m][n]);
      }
  }
#pragma unroll
  for (int m = 0; m < 2; ++m)
#pragma unroll
    for (int n = 0; n < 4; ++n) {
      const int r = t0 + tsub + n * 16 + ln15;
      if (r < cn) {
        const int ib = n0 + nsub + m * 16 + (lane >> 4) * 4;
        s16x4 o;
#pragma unroll
        for (int q = 0; q < 4; ++q)
          o[q] = f2bf(gelu_tanh(accg[m][n][q]) * accu[m][n][q]);
        *(s16x4*)(acte + (size_t)e * TOK * MID + (size_t)r * MID + ib) = o;
      }
    }
}

// ---------------- K6: expert down GEMM (128x128) + weighted scatter ------
__global__ __launch_bounds__(256) void k_exp_down(
    const short* __restrict__ wedT,   // [E][H][MI]
    const short* __restrict__ acte,   // [E][T][MI]
    const int* __restrict__ cnt, const int* __restrict__ tokl,
    const float* __restrict__ wgtl, const int* __restrict__ slotl,
    float* __restrict__ moep) {       // [2][T][H]
  const int e = blockIdx.z;
  const int cn = cnt[e];
  const int t0 = blockIdx.y * 128;
  if (t0 >= cn) return;
  const int n0 = blockIdx.x * 128;
  __shared__ short sW[128 * 32];
  __shared__ short sX[128 * 32];
  const int tid = threadIdx.x;
  const int lane = tid & 63, wave = tid >> 6;
  const int wr = wave >> 1, wc = wave & 1;
  const int ln15 = lane & 15, k8 = (lane >> 4) * 8;
  const int srow = tid >> 2, skc = (tid & 3) * 8;
  const short* wb = wedT + (size_t)e * HD * MID;
  const short* gW0 = wb + (size_t)(n0 + srow) * MID + skc;
  const short* gW1 = wb + (size_t)(n0 + 64 + srow) * MID + skc;
  const short* ab = acte + (size_t)e * TOK * MID;
  const short* gX0 = ab + (size_t)(t0 + srow) * MID + skc;
  const short* gX1 = ab + (size_t)(t0 + 64 + srow) * MID + skc;
  char* lW = (char*)sW + wave * 1024;
  char* lX = (char*)sX + wave * 1024;
  f32x4 acc[4][4];
#pragma unroll
  for (int m = 0; m < 4; ++m)
#pragma unroll
    for (int n = 0; n < 4; ++n) acc[m][n] = (f32x4)0.f;
  for (int kt = 0; kt < MID / 32; ++kt) {
    const int ko = kt * 32;
    __syncthreads();
    gload16(gW0 + ko, lW);
    gload16(gW1 + ko, lW + 4096);
    gload16(gX0 + ko, lX);
    gload16(gX1 + ko, lX + 4096);
    __syncthreads();
    s16x8 a[4], b[4];
#pragma unroll
    for (int m = 0; m < 4; ++m)
      a[m] = *(const s16x8*)(sW + (wr * 64 + m * 16 + ln15) * 32 + k8);
#pragma unroll
    for (int n = 0; n < 4; ++n)
      b[n] = *(const s16x8*)(sX + (wc * 64 + n * 16 + ln15) * 32 + k8);
#pragma unroll
    for (int m = 0; m < 4; ++m)
#pragma unroll
      for (int n = 0; n < 4; ++n) acc[m][n] = MFMA(a[m], b[n], acc[m][n]);
  }
#pragma unroll
  for (int n = 0; n < 4; ++n) {
    const int r = t0 + wc * 64 + n * 16 + ln15;
    if (r < cn) {
      const int tk = tokl[e * TOK + r];
      const float wf = wgtl[e * TOK + r];
      const int sl = slotl[e * TOK + r];
      float* dst = moep + (size_t)sl * TOK * HD + (size_t)tk * HD;
#pragma unroll
      for (int m = 0; m < 4; ++m) {
        const int h = n0 + wr * 64 + m * 16 + (lane >> 4) * 4;
        f32x4 v = acc[m][n] * wf;
        *(f32x4*)(dst + h) = v;
      }
    }
  }
}

// ---------------- K7: final triple RMSNorm fusion ------------------------
__global__ __launch_bounds__(256) void k_final(
    const float* __restrict__ dparts, const float* __restrict__ moep,
    const float* __restrict__ rno1, const float* __restrict__ rno2,
    const float* __restrict__ rnof, float* __restrict__ out) {
  const int t = blockIdx.x, tid = threadIdx.x;
  const size_t base = (size_t)t * HD;
  f32x4 dv[2], mv[2];
  float ssd = 0.f, ssm = 0.f;
#pragma unroll
  for (int i = 0; i < 2; ++i) {
    const int h = tid * 4 + i * 1024;
    dv[i] = (f32x4)0.f;
#pragma unroll
    for (int z = 0; z < KSPLIT; ++z)
      dv[i] += *(const f32x4*)(dparts + (size_t)z * TOK * HD + base + h);
    f32x4 a = *(const f32x4*)(moep + base + h);
    f32x4 b = *(const f32x4*)(moep + (size_t)TOK * HD + base + h);
    mv[i] = a + b;
#pragma unroll
    for (int j = 0; j < 4; ++j) { ssd += dv[i][j] * dv[i][j]; ssm += mv[i][j] * mv[i][j]; }
  }
  __shared__ float sr[8];
#pragma unroll
  for (int off = 32; off; off >>= 1) {
    ssd += __shfl_down(ssd, off, 64);
    ssm += __shfl_down(ssm, off, 64);
  }
  if ((tid & 63) == 0) { sr[tid >> 6] = ssd; sr[4 + (tid >> 6)] = ssm; }
  __syncthreads();
  const float invd = rsqrtf((sr[0] + sr[1] + sr[2] + sr[3]) * (1.0f / HD) + EPSF);
  const float invm = rsqrtf((sr[4] + sr[5] + sr[6] + sr[7]) * (1.0f / HD) + EPSF);
  f32x4 y[2];
  float ssy = 0.f;
#pragma unroll
  for (int i = 0; i < 2; ++i) {
    const int h = tid * 4 + i * 1024;
    f32x4 w1 = *(const f32x4*)(rno1 + h);
    f32x4 w2 = *(const f32x4*)(rno2 + h);
#pragma unroll
    for (int j = 0; j < 4; ++j) {
      y[i][j] = dv[i][j] * invd * w1[j] + mv[i][j] * invm * w2[j];
      ssy += y[i][j] * y[i][j];
    }
  }
  __syncthreads();
#pragma unroll
  for (int off = 32; off; off >>= 1) ssy += __shfl_down(ssy, off, 64);
  if ((tid & 63) == 0) sr[tid >> 6] = ssy;
  __syncthreads();
  const float invy = rsqrtf((sr[0] + sr[1] + sr[2] + sr[3]) * (1.0f / HD) + EPSF);
#pragma unroll
  for (int i = 0; i < 2; ++i) {
    const int h = tid * 4 + i * 1024;
    f32x4 w = *(const f32x4*)(rnof + h);
    f32x4 o;
#pragma unroll
    for (int j = 0; j < 4; ++j) o[j] = y[i][j] * invy * w[j];
    *(f32x4*)(out + base + h) = o;
  }
}

// ---------------- launcher ----------------------------------------------
extern "C" void kernel_launch(void* const* d_in, const int* in_sizes, int n_in,
                              void* d_out, int out_size, void* d_ws, size_t ws_size,
                              hipStream_t stream) {
  (void)in_sizes; (void)n_in; (void)out_size;
  const float* x    = (const float*)d_in[0];
  const float* rnp1 = (const float*)d_in[1];
  const float* rnp2 = (const float*)d_in[2];
  const float* rno1 = (const float*)d_in[3];
  const float* rno2 = (const float*)d_in[4];
  const float* rnof = (const float*)d_in[5];
  const float* wg   = (const float*)d_in[6];
  const float* wu   = (const float*)d_in[7];
  const float* wd   = (const float*)d_in[8];
  const float* rw   = (const float*)d_in[9];
  const float* rsc  = (const float*)d_in[10];
  const float* pes  = (const float*)d_in[11];
  const float* weg  = (const float*)d_in[12];
  const float* weu  = (const float*)d_in[13];
  const float* wed  = (const float*)d_in[14];
  float* out = (float*)d_out;

  char* ws = (char*)d_ws;
  size_t off = 0;
  auto alloc = [&](size_t bytes) -> void* {
    void* p = ws + off;
    off += (bytes + 255) & ~(size_t)255;
    return p;
  };
  const size_t IH  = (size_t)ID * HD;
  const size_t EMH = (size_t)NE * MID * HD;
  short* wgT   = (short*)alloc(IH * 2);   // wgT+wuT contiguous (67 MB):
  short* wuT   = (short*)alloc(IH * 2);   //   merged GEMM A; later dparts
  short* wdT   = (short*)alloc(IH * 2);
  short* wegT  = (short*)alloc(EMH * 2);
  short* weuT  = (short*)alloc(EMH * 2);
  short* wedT  = (short*)alloc(EMH * 2);
  short* rms1  = (short*)alloc((size_t)TOK * HD * 2);
  short* rms2  = (short*)alloc((size_t)TOK * HD * 2);
  short* actb  = (short*)alloc((size_t)TOK * ID * 2);
  short* acte  = (short*)alloc((size_t)NE * TOK * MID * 2);   // 33.5 MB  \ cbuf
  float* moep  = (float*)alloc((size_t)2 * TOK * HD * 4);     // 33.5 MB  / 67 MB
  int*   cnt   = (int*)alloc(NE * 4);
  int*   tokl  = (int*)alloc((size_t)NE * TOK * 4);
  float* wgtl  = (float*)alloc((size_t)NE * TOK * 4);
  int*   slotl = (int*)alloc((size_t)NE * TOK * 4);
  if (off > ws_size) return;  // workspace too small: bail cleanly
  // split-K partials alias wgT/wuT (dead after merged GEMM; exactly 64 MB)
  float* dparts = (float*)wgT;
  // merged gate|up GEMM output: acte+moep contiguous = TOK*ID2*2 = 64 MB
  short* cbuf = acte;

  hipMemsetAsync(cnt, 0, NE * 4, stream);
  k_rms_router<<<TOK, 256, 0, stream>>>(x, rnp1, rnp2, rsc, rw, pes,
                                        rms1, rms2, cnt, tokl, wgtl, slotl);
  k_transpose<<<dim3(ID / 64, HD / 64, 1), 256, 0, stream>>>(wg, wgT, HD, ID);
  k_transpose<<<dim3(ID / 64, HD / 64, 1), 256, 0, stream>>>(wu, wuT, HD, ID);
  k_transpose<<<dim3(HD / 64, ID / 64, 1), 256, 0, stream>>>(wd, wdT, ID, HD);
  k_transpose<<<dim3(MID / 64, HD / 64, NE), 256, 0, stream>>>(weg, wegT, HD, MID);
  k_transpose<<<dim3(MID / 64, HD / 64, NE), 256, 0, stream>>>(weu, weuT, HD, MID);
  k_transpose<<<dim3(HD / 64, MID / 64, NE), 256, 0, stream>>>(wed, wedT, MID, HD);
  k_gemm256<<<dim3(ID2 / 256, TOK / 256), 512, 0, stream>>>(wgT, rms1, cbuf);
  k_gelumul<<<(TOK * ID) / (256 * 8), 256, 0, stream>>>(cbuf, actb);
  k_dd256<<<dim3(HD / 256, TOK / 256, KSPLIT), 512, 0, stream>>>(wdT, actb, dparts);
  k_exp_gateup<<<dim3(MID / 64, TOK / 128, NE), 256, 0, stream>>>(wegT, weuT, rms2,
                                                                  cnt, tokl, acte);
  k_exp_down<<<dim3(HD / 128, TOK / 128, NE), 256, 0, stream>>>(wedT, acte, cnt, tokl,
                                                                wgtl, slotl, moep);
  k_final<<<TOK, 256, 0, stream>>>(dparts, moep, rno1, rno2, rnof, out);
}